// Round 3
// baseline (724.536 us; speedup 1.0000x reference)
//
#include <hip/hip_runtime.h>
#include <hip/hip_bf16.h>

typedef __attribute__((ext_vector_type(8))) __bf16 bf16x8;
typedef __attribute__((ext_vector_type(4))) __bf16 bf16x4;
typedef __attribute__((ext_vector_type(4))) float  f32x4;

#define L_LEN   8192
#define D_DIM   2048
#define G_NUM   256
#define HP      8320     // per-copy length of Hrev8 (elems), incl. 64-front/64-back zero pad
#define KVS     264      // LDS kv row stride (elems) -> 132 dwords, %32=4
#define HRING   2048     // h ring size per copy (elems), power of 2
#define HMSK    2047
#define HSTR    2088     // h copy stride (elems) -> 1044 dwords, %32=20 (bank spread)

// ---- pass 1: kv = x2*v, transpose (b,l,d) -> [g][c=b*8+dg][l], cast bf16 ----
__global__ __launch_bounds__(256) void prep_kv_kernel(
    const float* __restrict__ x2, const float* __restrict__ v,
    __bf16* __restrict__ kvout)
{
  __shared__ __bf16 sT[128 * 64];
  const int tid = threadIdx.x;
  const int l0 = blockIdx.x << 7;
  const int d0 = blockIdx.y << 6;
  const int b  = blockIdx.z;
  const int lr = tid >> 4;           // row-within-pass
  const int dq = tid & 15;           // d4-block
#pragma unroll
  for (int p = 0; p < 8; ++p) {
    const int ll = (p << 4) + lr;
    const size_t idx = ((size_t)(b * L_LEN + l0 + ll)) * D_DIM + d0 + (dq << 2);
    const f32x4 a = *(const f32x4*)&x2[idx];
    const f32x4 c = *(const f32x4*)&v[idx];
    bf16x4 kvv;
    kvv[0] = (__bf16)(a[0] * c[0]);
    kvv[1] = (__bf16)(a[1] * c[1]);
    kvv[2] = (__bf16)(a[2] * c[2]);
    kvv[3] = (__bf16)(a[3] * c[3]);
    *(bf16x4*)&sT[(ll << 6) + (((dq ^ (ll >> 3)) & 15) << 2)] = kvv;
  }
  __syncthreads();
#pragma unroll
  for (int p = 0; p < 2; ++p) {
    const int c  = tid + (p << 8);
    const int r  = c >> 3, seg = c & 7;   // r: d-local row, seg: 16-elem l-chunk
    const int rb = r >> 2, rl = r & 3;
    const int gch = d0 + r;
    const int row = ((gch >> 3) << 4) + (b << 3) + (gch & 7);  // g*16 + b*8 + dg
    bf16x8 w0, w1;
#pragma unroll
    for (int j = 0; j < 8; ++j) {
      const int lj0 = (seg << 4) + j;
      const int lj1 = lj0 + 8;
      w0[j] = sT[(lj0 << 6) + (((rb ^ (lj0 >> 3)) & 15) << 2) + rl];
      w1[j] = sT[(lj1 << 6) + (((rb ^ (lj1 >> 3)) & 15) << 2) + rl];
    }
    __bf16* dst = kvout + (size_t)row * L_LEN + l0 + (seg << 4);
    *(bf16x8*)dst = w0;
    *(bf16x8*)(dst + 8) = w1;
  }
}

// ---- pass 2: Hrev8[g][s][z] = Hrev(z - 64 + s), Hrev(x) = h[g][8191 - x] (0 outside) ----
__global__ __launch_bounds__(256) void prep_h_kernel(
    const float* __restrict__ h, __bf16* __restrict__ hr)
{
  const unsigned i = blockIdx.x * 256u + threadIdx.x;
  const unsigned g = i / (8u * HP);
  const unsigned r = i - g * (8u * HP);
  const unsigned s = r / HP;
  const unsigned z = r - s * HP;
  const int P = 8255 - (int)z - (int)s;
  __bf16 val = (__bf16)0.0f;
  if (P >= 0 && P < 8192) val = (__bf16)h[(size_t)g * 8192 + P];
  hr[i] = val;
}

// ---- pass 3: Toeplitz MFMA conv + bias + x1 gating + transpose-out ----
// One group g x 1024 l per block; 4 waves x 16 M-tiles (M=256/wave); N=16.
// K super-iter = 256 taps; A-frags in a rolling 16-register window keyed by
// f&15 where f = 15 + 2*jj - i: 30 ds_read_b128 feed 128 MFMAs (0.30 r/MFMA
// vs 0.47 before) -- LDS read BW is the per-CU shared-pipe bottleneck.
// h window lives in a single-buffered RING (slides +256/iter => stage only
// one bf16x8/thread/iter); kv stays double-buffered. Block mapping keeps all
// jb of a group on one XCD, temporally adjacent, for L2 kv/h reuse.
__global__ __launch_bounds__(256, 2) void conv_kernel(
    const __bf16* __restrict__ KV, const __bf16* __restrict__ HR,
    const float* __restrict__ x1, const float* __restrict__ bias,
    float* __restrict__ out)
{
  __shared__ __align__(16) __bf16 sKV[2][16 * KVS];
  __shared__ __align__(16) __bf16 sH[8 * HSTR];

  const int n   = blockIdx.x;
  const int xcd = n & 7, k = n >> 3;
  const int g   = ((k >> 3) << 3) | xcd;     // all 8 jb of g on same XCD, adjacent
  const int jb  = 7 - (k & 7);               // heavy l-blocks first per XCD
  const int l0  = jb << 10;
  const int tid = threadIdx.x;
  const int lane = tid & 63, wv = tid >> 6;
  const int m = lane & 15, q = lane >> 4;

  const __bf16* __restrict__ KVg = KV + (size_t)g * (16 * L_LEN);
  const __bf16* __restrict__ HRg = HR + (size_t)g * (8 * HP);

  f32x4 z4 = {0.f,0.f,0.f,0.f};
  f32x4 c0=z4,c1=z4,c2=z4,c3=z4,c4=z4,c5=z4,c6=z4,c7=z4,
        c8=z4,c9=z4,c10=z4,c11=z4,c12=z4,c13=z4,c14=z4,c15=z4;

  bf16x8 zed;
#pragma unroll
  for (int kk = 0; kk < 8; ++kk) zed[kk] = (__bf16)0.0f;

  const int cst = tid >> 4, tst = (tid & 15) << 3;  // kv staging: row, 8-elem chunk
  const int s_c   = (7 - m) & 7;                    // lane's shift-copy
  const int bbase = m * KVS + (q << 3);             // B-frag: n = lane&15, k-block = q
  const int wend  = l0 + (wv << 8) + 256;           // wave needs taps tb < wend
  const int hs_s  = tid >> 5;                       // h prefetch: copy
  const int hs_c  = (tid & 31) << 3;                //   chunk offset (elems)
  const int hwb   = hs_s * HSTR;

  const int nt = (l0 + 1024) >> 8;                  // super-iters (4..32)

  // ---- prologue: kv tile 0 -> sKV[0]; h window [YB0, YB0+1272) -> ring ----
  {
    *(bf16x8*)&sKV[0][cst * KVS + tst]       = *(const bf16x8*)&KVg[cst * L_LEN + tst];
    *(bf16x8*)&sKV[0][cst * KVS + tst + 128] = *(const bf16x8*)&KVg[cst * L_LEN + tst + 128];
    const int YB0 = 7232 - l0;   // = Bv(0) - 1023, already %8==0, >= 0
    for (int s = 0; s < 8; ++s) {
      for (int cc = tid; cc < 159; cc += 256) {
        const int y = YB0 + (cc << 3);
        bf16x8 w = (y + 8 <= HP) ? *(const bf16x8*)&HRg[s * HP + y] : zed;
        *(bf16x8*)&sH[s * HSTR + (y & HMSK)] = w;
      }
    }
  }
  __syncthreads();

  int cur = 0;
  bf16x8 pkv0, pkv1, ph;
  int py = 0;
  for (int t = 0; t < nt; ++t) {
    const int tb = t << 8;
    const bool pf = (t + 1 < nt);
    if (pf) {  // issue-early: next kv tile + the 256 new h elems per copy
      const int tbn = tb + 256;
      pkv0 = *(const bf16x8*)&KVg[cst * L_LEN + tbn + tst];
      pkv1 = *(const bf16x8*)&KVg[cst * L_LEN + tbn + tst + 128];
      py = 8504 - l0 + tb + hs_c;           // = YB(t) + 1272 + chunk
      ph = (py + 8 <= HP) ? *(const bf16x8*)&HRg[hs_s * HP + py] : zed;
    }

    if (tb < wend) {   // wave-uniform
      const __bf16* __restrict__ sKVc = sKV[cur];
      const __bf16* __restrict__ sHc  = sH + s_c * HSTR;
      const int Bv = 8255 - l0 + tb;
      const int ybase = Bv - (wv << 8) - m + (q << 3) - s_c - 240;

#define AFR(f) (*(const bf16x8*)&sHc[(ybase + ((f) << 4)) & HMSK])
#define BFR(j) (*(const bf16x8*)&sKVc[bbase + ((j) << 5)])
#define MF(ac, ar) ac = __builtin_amdgcn_mfma_f32_16x16x32_bf16(ar, bq, ac, 0, 0, 0)
      bf16x8 t0=AFR(0),t1=AFR(1),t2=AFR(2),t3=AFR(3),t4=AFR(4),t5=AFR(5),t6=AFR(6),t7=AFR(7),
             t8=AFR(8),t9=AFR(9),t10=AFR(10),t11=AFR(11),t12=AFR(12),t13=AFR(13),t14=AFR(14),t15=AFR(15);
      bf16x8 bq;
      bq = BFR(0);  // jj=0: f = 15 - i
      MF(c0,t15); MF(c1,t14); MF(c2,t13); MF(c3,t12); MF(c4,t11); MF(c5,t10); MF(c6,t9); MF(c7,t8);
      MF(c8,t7); MF(c9,t6); MF(c10,t5); MF(c11,t4); MF(c12,t3); MF(c13,t2); MF(c14,t1); MF(c15,t0);
      t0 = AFR(16); t1 = AFR(17); bq = BFR(1);  // jj=1: f = 17 - i
      MF(c0,t1); MF(c1,t0); MF(c2,t15); MF(c3,t14); MF(c4,t13); MF(c5,t12); MF(c6,t11); MF(c7,t10);
      MF(c8,t9); MF(c9,t8); MF(c10,t7); MF(c11,t6); MF(c12,t5); MF(c13,t4); MF(c14,t3); MF(c15,t2);
      t2 = AFR(18); t3 = AFR(19); bq = BFR(2);  // jj=2: f = 19 - i
      MF(c0,t3); MF(c1,t2); MF(c2,t1); MF(c3,t0); MF(c4,t15); MF(c5,t14); MF(c6,t13); MF(c7,t12);
      MF(c8,t11); MF(c9,t10); MF(c10,t9); MF(c11,t8); MF(c12,t7); MF(c13,t6); MF(c14,t5); MF(c15,t4);
      t4 = AFR(20); t5 = AFR(21); bq = BFR(3);  // jj=3: f = 21 - i
      MF(c0,t5); MF(c1,t4); MF(c2,t3); MF(c3,t2); MF(c4,t1); MF(c5,t0); MF(c6,t15); MF(c7,t14);
      MF(c8,t13); MF(c9,t12); MF(c10,t11); MF(c11,t10); MF(c12,t9); MF(c13,t8); MF(c14,t7); MF(c15,t6);
      t6 = AFR(22); t7 = AFR(23); bq = BFR(4);  // jj=4: f = 23 - i
      MF(c0,t7); MF(c1,t6); MF(c2,t5); MF(c3,t4); MF(c4,t3); MF(c5,t2); MF(c6,t1); MF(c7,t0);
      MF(c8,t15); MF(c9,t14); MF(c10,t13); MF(c11,t12); MF(c12,t11); MF(c13,t10); MF(c14,t9); MF(c15,t8);
      t8 = AFR(24); t9 = AFR(25); bq = BFR(5);  // jj=5: f = 25 - i
      MF(c0,t9); MF(c1,t8); MF(c2,t7); MF(c3,t6); MF(c4,t5); MF(c5,t4); MF(c6,t3); MF(c7,t2);
      MF(c8,t1); MF(c9,t0); MF(c10,t15); MF(c11,t14); MF(c12,t13); MF(c13,t12); MF(c14,t11); MF(c15,t10);
      t10 = AFR(26); t11 = AFR(27); bq = BFR(6);  // jj=6: f = 27 - i
      MF(c0,t11); MF(c1,t10); MF(c2,t9); MF(c3,t8); MF(c4,t7); MF(c5,t6); MF(c6,t5); MF(c7,t4);
      MF(c8,t3); MF(c9,t2); MF(c10,t1); MF(c11,t0); MF(c12,t15); MF(c13,t14); MF(c14,t13); MF(c15,t12);
      t12 = AFR(28); t13 = AFR(29); bq = BFR(7);  // jj=7: f = 29 - i
      MF(c0,t13); MF(c1,t12); MF(c2,t11); MF(c3,t10); MF(c4,t9); MF(c5,t8); MF(c6,t7); MF(c7,t6);
      MF(c8,t5); MF(c9,t4); MF(c10,t3); MF(c11,t2); MF(c12,t1); MF(c13,t0); MF(c14,t15); MF(c15,t14);
#undef MF
#undef BFR
#undef AFR
    }

    if (pf) {  // write-late; ring slots [YB+1272,+1528) disjoint from window [YB,+1272)
      *(bf16x8*)&sKV[cur ^ 1][cst * KVS + tst]       = pkv0;
      *(bf16x8*)&sKV[cur ^ 1][cst * KVS + tst + 128] = pkv1;
      *(bf16x8*)&sH[hwb + (py & HMSK)] = ph;
    }
    __syncthreads();
    cur ^= 1;
  }

  // epilogue: y += kv*bias; out = x1 * y, scattered back to (b,l,d)
  const int c = m;
  const int bb = c >> 3, dg = c & 7;
  const float bv = bias[(g << 3) + dg];

#define CONV_EPI(i, accv) {                                                     \
    const int l = l0 + (wv << 8) + ((i) << 4) + (q << 2);                       \
    const bf16x4 kv4 = *(const bf16x4*)&KVg[c * L_LEN + l];                     \
    for (int r = 0; r < 4; ++r) {                                               \
      const float y = accv[r] + (float)kv4[r] * bv;                             \
      const size_t oidx = ((size_t)(bb * L_LEN + l + r)) * D_DIM + (g << 3) + dg;\
      out[oidx] = x1[oidx] * y;                                                 \
    } }

  CONV_EPI(0,  c0)  CONV_EPI(1,  c1)  CONV_EPI(2,  c2)  CONV_EPI(3,  c3)
  CONV_EPI(4,  c4)  CONV_EPI(5,  c5)  CONV_EPI(6,  c6)  CONV_EPI(7,  c7)
  CONV_EPI(8,  c8)  CONV_EPI(9,  c9)  CONV_EPI(10, c10) CONV_EPI(11, c11)
  CONV_EPI(12, c12) CONV_EPI(13, c13) CONV_EPI(14, c14) CONV_EPI(15, c15)
#undef CONV_EPI
}

extern "C" void kernel_launch(void* const* d_in, const int* in_sizes, int n_in,
                              void* d_out, int out_size, void* d_ws, size_t ws_size,
                              hipStream_t stream)
{
  const float* x1 = (const float*)d_in[0];
  const float* x2 = (const float*)d_in[1];
  const float* v  = (const float*)d_in[2];
  const float* h  = (const float*)d_in[3];
  const float* cb = (const float*)d_in[4];
  float* out = (float*)d_out;

  // workspace: kv bf16 [256][16][8192] = 64 MiB, then Hrev8 bf16 [256][8][8320] = 32.5 MiB
  __bf16* kv = (__bf16*)d_ws;
  __bf16* hr = kv + (size_t)G_NUM * 16 * L_LEN;

  prep_kv_kernel<<<dim3(L_LEN / 128, D_DIM / 64, 2), 256, 0, stream>>>(x2, v, kv);
  prep_h_kernel<<<(G_NUM * 8 * HP) / 256, 256, 0, stream>>>(h, hr);
  conv_kernel<<<2048, 256, 0, stream>>>(kv, hr, x1, cb, out);
}